// Round 1
// baseline (849.355 us; speedup 1.0000x reference)
//
#include <hip/hip_runtime.h>

// Viterbi / CRF decode: B=32, S=512, T=128.
// One workgroup per batch; forward max-plus scan with backpointers kept in LDS
// (uchar[512][128] = 64KB), then local backtrack. Exact fp-order match with the
// numpy reference: cur = (fs[i] + t1[j]) + t0[i,j]; argmax = first max (smallest i).

constexpr int S = 512;
constexpr int T = 128;

__global__ __launch_bounds__(1024, 1)
void viterbi_fused(const float* __restrict__ c0, const float* __restrict__ c1,
                   const int* __restrict__ sofp, const int* __restrict__ eofp,
                   int* __restrict__ out)
{
    __shared__ float fs[2][T];            // ping-pong forward scores
    __shared__ float pmax[32][T];         // per-i-group partial max
    __shared__ int   parg[32][T];         // per-i-group partial argmax
    __shared__ unsigned char bp[S][T];    // backpointers, 64 KB

    const int b   = blockIdx.x;
    const int tid = (int)threadIdx.x;
    const int jq  = tid & 31;             // j-quad index: j = 4*jq .. 4*jq+3
    const int g   = tid >> 5;             // i-group 0..31: i = 4*g .. 4*g+3
    const int col = jq * 4;
    const int row = g * 4;

    const float* c0b = c0 + (size_t)b * (S + 1) * T * T;
    const float* c1b = c1 + (size_t)b * (S + 1) * T;

    // Initial scores: fs[j] = c0[b,0,sof,j] * c1[b,0,j]  (multiply, per reference)
    if (tid < T) {
        const int sof = sofp[0];
        fs[0][tid] = c0b[(size_t)sof * T + tid] * c1b[tid];
    }
    __syncthreads();

    // Prologue: load step s=1 tile into registers.
    {
    }
    const float* t0p = c0b + (size_t)1 * T * T;
    const float* t1p = c1b + (size_t)1 * T;
    float4 a0 = *(const float4*)(t0p + (size_t)(row + 0) * T + col);
    float4 a1 = *(const float4*)(t0p + (size_t)(row + 1) * T + col);
    float4 a2 = *(const float4*)(t0p + (size_t)(row + 2) * T + col);
    float4 a3 = *(const float4*)(t0p + (size_t)(row + 3) * T + col);
    float4 tv = *(const float4*)(t1p + col);

    int p = 0;
    for (int s = 1; s <= S; ++s) {
        // Issue next step's loads early (independent of fs) so they are in
        // flight across the compute + barriers of this step.
        float4 b0 = make_float4(0.f,0.f,0.f,0.f), b1 = b0, b2 = b0, b3 = b0, bt = b0;
        if (s < S) {
            const float* n0 = c0b + (size_t)(s + 1) * T * T;
            const float* n1 = c1b + (size_t)(s + 1) * T;
            b0 = *(const float4*)(n0 + (size_t)(row + 0) * T + col);
            b1 = *(const float4*)(n0 + (size_t)(row + 1) * T + col);
            b2 = *(const float4*)(n0 + (size_t)(row + 2) * T + col);
            b3 = *(const float4*)(n0 + (size_t)(row + 3) * T + col);
            bt = *(const float4*)(n1 + col);
        }

        const float f0 = fs[p][row + 0];
        const float f1 = fs[p][row + 1];
        const float f2 = fs[p][row + 2];
        const float f3 = fs[p][row + 3];

        // Per-thread 4x4 tile: best over 4 i's for each of 4 j's.
        // Exact ref order: (fs[i] + t1[j]) + t0[i,j]; strict > keeps first max.
        float bx, by, bz, bw; int ix, iy, iz, iw; float v;
        bx = (f0 + tv.x) + a0.x; ix = row;
        by = (f0 + tv.y) + a0.y; iy = row;
        bz = (f0 + tv.z) + a0.z; iz = row;
        bw = (f0 + tv.w) + a0.w; iw = row;

        v = (f1 + tv.x) + a1.x; if (v > bx) { bx = v; ix = row + 1; }
        v = (f1 + tv.y) + a1.y; if (v > by) { by = v; iy = row + 1; }
        v = (f1 + tv.z) + a1.z; if (v > bz) { bz = v; iz = row + 1; }
        v = (f1 + tv.w) + a1.w; if (v > bw) { bw = v; iw = row + 1; }

        v = (f2 + tv.x) + a2.x; if (v > bx) { bx = v; ix = row + 2; }
        v = (f2 + tv.y) + a2.y; if (v > by) { by = v; iy = row + 2; }
        v = (f2 + tv.z) + a2.z; if (v > bz) { bz = v; iz = row + 2; }
        v = (f2 + tv.w) + a2.w; if (v > bw) { bw = v; iw = row + 2; }

        v = (f3 + tv.x) + a3.x; if (v > bx) { bx = v; ix = row + 3; }
        v = (f3 + tv.y) + a3.y; if (v > by) { by = v; iy = row + 3; }
        v = (f3 + tv.z) + a3.z; if (v > bz) { bz = v; iz = row + 3; }
        v = (f3 + tv.w) + a3.w; if (v > bw) { bw = v; iw = row + 3; }

        *(float4*)&pmax[g][col] = make_float4(bx, by, bz, bw);
        *(int4*)  &parg[g][col] = make_int4(ix, iy, iz, iw);
        __syncthreads();

        // Final reduce over the 32 i-groups; ascending g preserves first-max.
        if (tid < T) {
            float bb = pmax[0][tid];
            int   ii = parg[0][tid];
            #pragma unroll
            for (int gg = 1; gg < 32; ++gg) {
                float vv = pmax[gg][tid];
                if (vv > bb) { bb = vv; ii = parg[gg][tid]; }
            }
            fs[p ^ 1][tid] = bb;
            bp[s - 1][tid] = (unsigned char)ii;
        }
        __syncthreads();

        p ^= 1;
        a0 = b0; a1 = b1; a2 = b2; a3 = b3; tv = bt;
    }

    // Backtrack (serial per batch, all in LDS):
    // ptr = bp[S-1][eof]; for idx = S-1..0: ptr = bp[idx][ptr]; out[b,idx] = ptr.
    if (tid == 0) {
        const int eof = eofp[0];
        int ptr = bp[S - 1][eof];
        for (int idx = S - 1; idx >= 0; --idx) {
            ptr = bp[idx][ptr];
            out[(size_t)b * S + idx] = ptr;
        }
    }
}

extern "C" void kernel_launch(void* const* d_in, const int* in_sizes, int n_in,
                              void* d_out, int out_size, void* d_ws, size_t ws_size,
                              hipStream_t stream)
{
    const float* c0  = (const float*)d_in[0];
    const float* c1  = (const float*)d_in[1];
    const int*   sof = (const int*)d_in[2];
    const int*   eof = (const int*)d_in[3];
    int*         out = (int*)d_out;

    const int B = in_sizes[1] / ((S + 1) * T);   // 32
    viterbi_fused<<<dim3(B), dim3(1024), 0, stream>>>(c0, c1, sof, eof, out);
}

// Round 2
// 821.838 us; speedup vs baseline: 1.0335x; 1.0335x over previous
//
#include <hip/hip_runtime.h>

// Viterbi / CRF decode: B=32, S=512, T=128.
// One workgroup per batch. Key fix vs R1: __syncthreads() drains vmcnt(0)
// (workgroup fence), killing the global prefetch. All cross-wave traffic here
// is LDS, so we barrier with lgkmcnt(0) ONLY — global loads stay in flight
// across barriers (T4 idiom). 2-deep software pipeline (reg sets A/B).
// Exact fp-order match with reference: cur = (fs[i] + t1[j]) + t0[i,j];
// argmax = first max (smallest i) via strict-> compare in ascending i order.

constexpr int S = 512;
constexpr int T = 128;

__device__ __forceinline__ void bar_lds() {
    // Wait only for LDS ops, then barrier. Does NOT drain vmcnt -> global
    // prefetch loads remain in flight across the barrier.
    asm volatile("s_waitcnt lgkmcnt(0)" ::: "memory");
    __builtin_amdgcn_s_barrier();
}

__global__ __launch_bounds__(1024, 1)
void viterbi_fused(const float* __restrict__ c0, const float* __restrict__ c1,
                   const int* __restrict__ sofp, const int* __restrict__ eofp,
                   int* __restrict__ out)
{
    __shared__ float fs[2][T];            // ping-pong forward scores
    __shared__ float pmax[16][T];         // per-wave-pair partial max
    __shared__ int   parg[16][T];         // per-wave-pair partial argmax
    __shared__ unsigned char bp[S][T];    // backpointers, 64 KB

    const int b    = blockIdx.x;
    const int tid  = (int)threadIdx.x;
    const int lane = tid & 63;
    const int w    = tid >> 6;            // wave 0..15
    const int jq   = lane & 31;           // j-quad: j = 4*jq .. 4*jq+3
    const int g    = tid >> 5;            // i-group 0..31: i = 4*g .. 4*g+3
    const int col  = jq * 4;
    const int row  = g * 4;

    const float* c0b = c0 + (size_t)b * (S + 1) * T * T;
    const float* c1b = c1 + (size_t)b * (S + 1) * T;

    // Initial scores: fs[j] = c0[b,0,sof,j] * c1[b,0,j]  (multiply, per ref)
    if (tid < T) {
        const int sof = sofp[0];
        fs[0][tid] = c0b[(size_t)sof * T + tid] * c1b[tid];
    }

    // Prologue: load step 1 -> A, step 2 -> B.
    float4 A0, A1, A2, A3, At, B0, B1, B2, B3, Bt;
    {
        const float* t0p = c0b + (size_t)1 * T * T;
        A0 = *(const float4*)(t0p + (size_t)(row + 0) * T + col);
        A1 = *(const float4*)(t0p + (size_t)(row + 1) * T + col);
        A2 = *(const float4*)(t0p + (size_t)(row + 2) * T + col);
        A3 = *(const float4*)(t0p + (size_t)(row + 3) * T + col);
        At = *(const float4*)(c1b + (size_t)1 * T + col);
        const float* u0p = c0b + (size_t)2 * T * T;
        B0 = *(const float4*)(u0p + (size_t)(row + 0) * T + col);
        B1 = *(const float4*)(u0p + (size_t)(row + 1) * T + col);
        B2 = *(const float4*)(u0p + (size_t)(row + 2) * T + col);
        B3 = *(const float4*)(u0p + (size_t)(row + 3) * T + col);
        Bt = *(const float4*)(c1b + (size_t)2 * T + col);
    }
    bar_lds();  // fs[0] visible to all

    int p = 0;

    auto STEP = [&](int s, float4& a0, float4& a1, float4& a2, float4& a3,
                    float4& tv) {
        const float f0 = fs[p][row + 0];
        const float f1 = fs[p][row + 1];
        const float f2 = fs[p][row + 2];
        const float f3 = fs[p][row + 3];

        // Per-thread 4x4 tile, exact ref order, strict > keeps first (lowest i).
        float bx, by, bz, bw; int ix, iy, iz, iw; float v;
        bx = (f0 + tv.x) + a0.x; ix = row;
        by = (f0 + tv.y) + a0.y; iy = row;
        bz = (f0 + tv.z) + a0.z; iz = row;
        bw = (f0 + tv.w) + a0.w; iw = row;

        v = (f1 + tv.x) + a1.x; if (v > bx) { bx = v; ix = row + 1; }
        v = (f1 + tv.y) + a1.y; if (v > by) { by = v; iy = row + 1; }
        v = (f1 + tv.z) + a1.z; if (v > bz) { bz = v; iz = row + 1; }
        v = (f1 + tv.w) + a1.w; if (v > bw) { bw = v; iw = row + 1; }

        v = (f2 + tv.x) + a2.x; if (v > bx) { bx = v; ix = row + 2; }
        v = (f2 + tv.y) + a2.y; if (v > by) { by = v; iy = row + 2; }
        v = (f2 + tv.z) + a2.z; if (v > bz) { bz = v; iz = row + 2; }
        v = (f2 + tv.w) + a2.w; if (v > bw) { bw = v; iw = row + 2; }

        v = (f3 + tv.x) + a3.x; if (v > bx) { bx = v; ix = row + 3; }
        v = (f3 + tv.y) + a3.y; if (v > by) { by = v; iy = row + 3; }
        v = (f3 + tv.z) + a3.z; if (v > bz) { bz = v; iz = row + 3; }
        v = (f3 + tv.w) + a3.w; if (v > bw) { bw = v; iw = row + 3; }

        // Prefetch step s+2 into this (now dead) register set. Issued here so
        // it has ~1.5 iterations of flight time; no barrier below drains vmcnt.
        if (s + 2 <= S) {
            const float* n0 = c0b + (size_t)(s + 2) * T * T;
            a0 = *(const float4*)(n0 + (size_t)(row + 0) * T + col);
            a1 = *(const float4*)(n0 + (size_t)(row + 1) * T + col);
            a2 = *(const float4*)(n0 + (size_t)(row + 2) * T + col);
            a3 = *(const float4*)(n0 + (size_t)(row + 3) * T + col);
            tv = *(const float4*)(c1b + (size_t)(s + 2) * T + col);
        }

        // Combine the wave's two i-groups (2w: lanes<32, 2w+1: lanes>=32).
        // Lanes<32 hold the LOWER i range; partner strictly greater wins.
        float cx = __shfl_xor(bx, 32, 64);
        float cy = __shfl_xor(by, 32, 64);
        float cz = __shfl_xor(bz, 32, 64);
        float cw = __shfl_xor(bw, 32, 64);
        int   dx = __shfl_xor(ix, 32, 64);
        int   dy = __shfl_xor(iy, 32, 64);
        int   dz = __shfl_xor(iz, 32, 64);
        int   dw = __shfl_xor(iw, 32, 64);
        if (lane < 32) {
            if (cx > bx) { bx = cx; ix = dx; }
            if (cy > by) { by = cy; iy = dy; }
            if (cz > bz) { bz = cz; iz = dz; }
            if (cw > bw) { bw = cw; iw = dw; }
            *(float4*)&pmax[w][col] = make_float4(bx, by, bz, bw);
            *(int4*)  &parg[w][col] = make_int4(ix, iy, iz, iw);
        }
        bar_lds();

        // Final reduce over 16 wave-partials; ascending w preserves first-max.
        if (tid < T) {
            float bb = pmax[0][tid];
            int   ii = parg[0][tid];
            #pragma unroll
            for (int gg = 1; gg < 16; ++gg) {
                float vv = pmax[gg][tid];
                if (vv > bb) { bb = vv; ii = parg[gg][tid]; }
            }
            fs[p ^ 1][tid] = bb;
            bp[s - 1][tid] = (unsigned char)ii;
        }
        bar_lds();
        p ^= 1;
    };

    for (int s = 1; s <= S; s += 2) {
        STEP(s,     A0, A1, A2, A3, At);
        STEP(s + 1, B0, B1, B2, B3, Bt);
    }

    // Backtrack (serial pointer chase, all in LDS).
    if (tid == 0) {
        const int eof = eofp[0];
        int ptr = bp[S - 1][eof];
        for (int idx = S - 1; idx >= 0; --idx) {
            ptr = bp[idx][ptr];
            out[(size_t)b * S + idx] = ptr;
        }
    }
}

extern "C" void kernel_launch(void* const* d_in, const int* in_sizes, int n_in,
                              void* d_out, int out_size, void* d_ws, size_t ws_size,
                              hipStream_t stream)
{
    const float* c0  = (const float*)d_in[0];
    const float* c1  = (const float*)d_in[1];
    const int*   sof = (const int*)d_in[2];
    const int*   eof = (const int*)d_in[3];
    int*         out = (int*)d_out;

    const int B = in_sizes[1] / ((S + 1) * T);   // 32
    viterbi_fused<<<dim3(B), dim3(1024), 0, stream>>>(c0, c1, sof, eof, out);
}